// Round 11
// baseline (108.948 us; speedup 1.0000x reference)
//
#include <hip/hip_runtime.h>
#include <hip/hip_bf16.h>
#include <hip/hip_fp16.h>

// Triangle attention (starting node), b=1, n=256, d=128, H=4, DH=32.
// Round 10: LN + bias GEMV fused into the qkvg GEMM's A-staging (kernel
// count 5->4, removes 16MB Xb write + 16MB read). Attn unchanged from
// round 9 (lane-local PV fragments, 128 VGPR, 4 blk/CU).

#define NP  256
#define DD  128
#define HSTR 2097152   // 65536*32, per-head block stride (elements)

typedef short bf16x8 __attribute__((ext_vector_type(8)));
typedef float f32x4  __attribute__((ext_vector_type(4)));

__device__ __forceinline__ float bf2f(ushort u) {
    union { unsigned int v; float f; } c; c.v = ((unsigned int)u) << 16; return c.f;
}
__device__ __forceinline__ float asf(unsigned int v) {
    union { unsigned int v; float f; } c; c.v = v; return c.f;
}
__device__ __forceinline__ ushort f2bf(float f) {
    union { float f; unsigned int v; } c; c.f = f;
    unsigned int x = c.v;
    return (ushort)((x + 0x7FFFu + ((x >> 16) & 1u)) >> 16);  // RNE
}
__device__ __forceinline__ unsigned int packbf(float a, float b) {
    __hip_bfloat162 t = __float22bfloat162_rn(make_float2(a, b));  // a -> low
    union { __hip_bfloat162 h; unsigned int u; } c; c.h = t; return c.u;
}
__device__ __forceinline__ f32x4 mfma16(bf16x8 a, bf16x8 b, f32x4 c) {
    return __builtin_amdgcn_mfma_f32_16x16x32_bf16(a, b, c, 0, 0, 0);
}

#define NEGV (-3.4028234663852886e38f)
#define SCALE 0.17677669529663687f

// ---------------- K0: W -> bf16, transposed (N-major, K-contiguous) --------
__global__ __launch_bounds__(256) void k_wconv(
    const float* __restrict__ Wqkv, const float* __restrict__ Wg,
    const float* __restrict__ Wout, ushort* __restrict__ WT,
    ushort* __restrict__ WoT)
{
    int idx = blockIdx.x * 256 + threadIdx.x;   // grid 320 -> 81920
    if (idx < 65536) {
        int n = idx >> 7, k = idx & 127;
        float v = (n < 384) ? Wqkv[(size_t)k * 384 + n]
                            : Wg[(size_t)k * 128 + (n - 384)];
        WT[idx] = f2bf(v);
    } else {
        int i2 = idx - 65536;
        int c = i2 >> 7, e = i2 & 127;
        WoT[i2] = f2bf(Wout[(size_t)e * 128 + c]);
    }
}

// ---------------- K1: fused LN + bias GEMV + x @ [Wqkv|Wg] MFMA GEMM -------
// grid 1024 x 256 thr. LN normalizes the block's 64 rows straight into the
// bf16 A-tile (LDS); bias GEMV reads the A-tile; then 4 N-segments loop.
__global__ __launch_bounds__(256) void k_lnqkvg(
    const float* __restrict__ edges, const float* __restrict__ gamma,
    const float* __restrict__ beta,  const float* __restrict__ Wb,
    const ushort* __restrict__ WT,   const float* __restrict__ bg,
    ushort* __restrict__ Bo16,
    ushort* __restrict__ Qo, ushort* __restrict__ Ko,
    ushort* __restrict__ Vo, ushort* __restrict__ Go)
{
    __shared__ __align__(16) ushort As[64][136];
    __shared__ __align__(16) ushort Bs[128][136];
    const int tid = threadIdx.x, w = tid >> 6, lane = tid & 63;
    const int p0 = blockIdx.x * 64;

    // --- LN phase: wave w handles rows w*16..w*16+15 -> bf16 into As ---
    {
        const float g0 = gamma[lane], g1 = gamma[lane + 64];
        const float b0 = beta[lane],  b1 = beta[lane + 64];
        for (int pp = 0; pp < 16; ++pp) {
            const int row = w * 16 + pp;
            const float* ep = edges + (size_t)(p0 + row) * DD;
            float e0 = ep[lane], e1 = ep[lane + 64];
            float s = e0 + e1;
            #pragma unroll
            for (int off = 1; off < 64; off <<= 1) s += __shfl_xor(s, off);
            float mu = s * 0.0078125f;
            float d0 = e0 - mu, d1 = e1 - mu;
            float ss = d0 * d0 + d1 * d1;
            #pragma unroll
            for (int off = 1; off < 64; off <<= 1) ss += __shfl_xor(ss, off);
            float rstd = rsqrtf(ss * 0.0078125f + 1e-5f);
            As[row][lane]      = f2bf(d0 * rstd * g0 + b0);
            As[row][lane + 64] = f2bf(d1 * rstd * g1 + b1);
        }
    }
    __syncthreads();
    // --- bias GEMV: thread=(row r, head hh); x from As (bf16) ---
    {
        const int r = tid >> 2, hh = tid & 3;
        float acc = 0.f;
        for (int e = 0; e < DD; ++e) acc += bf2f(As[r][e]) * Wb[e * 4 + hh];
        const int p = p0 + r;
        const int j = p >> 8, k = p & 255;
        const int fn = k >> 4, lgk = (k >> 2) & 3, rr = k & 3;
        Bo16[(size_t)hh * 65536 + (((size_t)j * 4 + lgk) * 16 + fn) * 4 + rr] = f2bf(acc);
    }

    const int wm = w >> 1, wn = w & 1;
    const int lr = lane & 15, lg = lane >> 4;
    const f32x4 zz = {0.f, 0.f, 0.f, 0.f};

    for (int seg = 0; seg < 4; ++seg) {
        const int n0 = seg * 128;
        __syncthreads();   // prev-seg Bs reads done; (seg 0: bias reads done)
        #pragma unroll
        for (int it = 0; it < 8; ++it) {
            int idx = it * 256 + tid;
            int r = idx >> 4, c = (idx & 15) * 8;
            *reinterpret_cast<uint4*>(&Bs[r][c]) =
                *reinterpret_cast<const uint4*>(&WT[(size_t)(n0 + r) * DD + c]);
        }
        __syncthreads();
        f32x4 acc[2][4];
        #pragma unroll
        for (int m = 0; m < 2; ++m)
            #pragma unroll
            for (int n = 0; n < 4; ++n) acc[m][n] = zz;
        #pragma unroll
        for (int kk = 0; kk < 4; ++kk) {
            bf16x8 a0 = *reinterpret_cast<const bf16x8*>(&As[wm * 32 + lr][kk * 32 + lg * 8]);
            bf16x8 a1 = *reinterpret_cast<const bf16x8*>(&As[wm * 32 + 16 + lr][kk * 32 + lg * 8]);
            #pragma unroll
            for (int n = 0; n < 4; ++n) {
                bf16x8 b = *reinterpret_cast<const bf16x8*>(&Bs[wn * 64 + n * 16 + lr][kk * 32 + lg * 8]);
                acc[0][n] = mfma16(a0, b, acc[0][n]);
                acc[1][n] = mfma16(a1, b, acc[1][n]);
            }
        }
        #pragma unroll
        for (int n = 0; n < 4; ++n) {
            const int cc = wn * 64 + n * 16 + lr;
            const int hh = cc >> 5, dh = cc & 31;
            const float bgv = (seg == 3) ? bg[cc] : 0.f;
            #pragma unroll
            for (int m = 0; m < 2; ++m) {
                #pragma unroll
                for (int r = 0; r < 4; ++r) {
                    const int p = p0 + wm * 32 + m * 16 + lg * 4 + r;
                    const float v = acc[m][n][r];
                    const size_t off = (size_t)hh * HSTR + (size_t)p * 32 + dh;
                    if (seg == 0)      Qo[off] = f2bf(v * SCALE);
                    else if (seg == 1) Ko[off] = f2bf(v);
                    else if (seg == 2) Vo[off] = f2bf(v);
                    else Go[off] = f2bf(1.0f / (1.0f + __expf(-(v + bgv))));
                }
            }
        }
    }
}

// ---------------- K2: attention; lane-local PV fragments -------------------
// grid 1024 (1 (i,h) per block). h=(bid&7)>>1 groups heads per XCD (bias
// slice L2-resident). V^T columns key-permuted so packed P words ARE the
// PV B-fragment (no LDS round-trip, no shuffles). launch_bounds(256,2)
// -> 128 VGPR (no spill); LDS 37.9KB + VGPR 128 allow 4 blocks/CU.
__global__ __launch_bounds__(256, 2) void k_attn9(
    const ushort* __restrict__ Qw, const ushort* __restrict__ Kw,
    const ushort* __restrict__ Vw, const ushort* __restrict__ Bo16,
    const int* __restrict__ mask, ushort* __restrict__ OPre)
{
    __shared__ __align__(16) ushort Ks[256][40];   // K rows: 20.0KB
    __shared__ __align__(16) ushort Vt[32][268];   // V^T (key-permuted): 16.75KB
    const int tid = threadIdx.x, w = tid >> 6, lane = tid & 63;
    const int lr = lane & 15, lg = lane >> 4;
    const int bid = blockIdx.x;
    const int h = (bid & 7) >> 1;
    const int i = ((bid >> 3) << 1) | (bid & 1);
    const int ib = i * NP;
    const size_t base = (size_t)h * HSTR + (size_t)ib * 32;   // + k*32 + dh

    #pragma unroll
    for (int it = 0; it < 4; ++it) {
        int idx = it * 256 + tid;
        int r = idx >> 2, c = (idx & 3) * 8;
        *reinterpret_cast<uint4*>(&Ks[r][c]) =
            *reinterpret_cast<const uint4*>(&Kw[base + (size_t)r * 32 + c]);
    }
    #pragma unroll
    for (int it = 0; it < 8; ++it) {
        int idx = it * 256 + tid;
        int d = idx & 31, k4 = (idx >> 5) * 4;
        int kk4 = (k4 & ~31) | (((k4 >> 2) & 1) << 4) | (((k4 >> 3) & 3) << 2);
        ushort4 v;
        v.x = Vw[base + (size_t)(kk4 + 0) * 32 + d];
        v.y = Vw[base + (size_t)(kk4 + 1) * 32 + d];
        v.z = Vw[base + (size_t)(kk4 + 2) * 32 + d];
        v.w = Vw[base + (size_t)(kk4 + 3) * 32 + d];
        *reinterpret_cast<ushort4*>(&Vt[d][k4]) = v;
    }
    __syncthreads();

    const ushort* bias_h = Bo16 + (size_t)h * 65536;
    const f32x4 zz = {0.f, 0.f, 0.f, 0.f};

    for (int jt = 0; jt < 4; ++jt) {
        const int jb = jt * 64 + w * 16;
        const int jq = jb + lr;             // this lane's softmax row
        bf16x8 q = *reinterpret_cast<const bf16x8*>(&Qw[base + (size_t)jq * 32 + lg * 8]);
        const ushort* bp = bias_h + ((size_t)jq * 4 + lg) * 64;
        f32x4 s[16];
        #pragma unroll
        for (int u = 0; u < 8; ++u) {
            uint4 b4 = *reinterpret_cast<const uint4*>(bp + u * 8);
            f32x4 s0, s1;
            s0[0] = asf(b4.x << 16); s0[1] = asf(b4.x & 0xffff0000u);
            s0[2] = asf(b4.y << 16); s0[3] = asf(b4.y & 0xffff0000u);
            s1[0] = asf(b4.z << 16); s1[1] = asf(b4.z & 0xffff0000u);
            s1[2] = asf(b4.w << 16); s1[3] = asf(b4.w & 0xffff0000u);
            s[2 * u] = s0; s[2 * u + 1] = s1;
        }
        #pragma unroll
        for (int fn = 0; fn < 16; ++fn) {
            bf16x8 a = *reinterpret_cast<const bf16x8*>(&Ks[fn * 16 + lr][lg * 8]);
            s[fn] = mfma16(a, q, s[fn]);    // S^T[k][j]
        }
        float mx = -3.402823466e38f;
        #pragma unroll
        for (int fn = 0; fn < 16; ++fn) {
            float m01 = fmaxf(s[fn][0], s[fn][1]);
            float m23 = fmaxf(s[fn][2], s[fn][3]);
            mx = fmaxf(mx, fmaxf(m01, m23));
        }
        mx = fmaxf(mx, __shfl_xor(mx, 16));
        mx = fmaxf(mx, __shfl_xor(mx, 32));
        float sum = 0.f;
        #pragma unroll
        for (int fn = 0; fn < 16; ++fn) {
            #pragma unroll
            for (int r = 0; r < 4; ++r) {
                float e = __expf(s[fn][r] - mx);
                s[fn][r] = e; sum += e;
            }
        }
        sum += __shfl_xor(sum, 16);
        sum += __shfl_xor(sum, 32);
        const bool masked = (mask[ib + jq] == 0);
        const float iv = masked ? 1.0f : (1.0f / sum);

        f32x4 o0 = zz, o1 = zz;
        #pragma unroll
        for (int m = 0; m < 8; ++m) {
            union { unsigned int u[4]; bf16x8 v; } pa;
            pa.u[0] = masked ? 0x3B803B80u : packbf(s[2 * m][0], s[2 * m][1]);
            pa.u[1] = masked ? 0x3B803B80u : packbf(s[2 * m][2], s[2 * m][3]);
            pa.u[2] = masked ? 0x3B803B80u : packbf(s[2 * m + 1][0], s[2 * m + 1][1]);
            pa.u[3] = masked ? 0x3B803B80u : packbf(s[2 * m + 1][2], s[2 * m + 1][3]);
            bf16x8 v0 = *reinterpret_cast<const bf16x8*>(&Vt[lr][m * 32 + lg * 8]);
            bf16x8 v1 = *reinterpret_cast<const bf16x8*>(&Vt[16 + lr][m * 32 + lg * 8]);
            o0 = mfma16(v0, pa.v, o0);
            o1 = mfma16(v1, pa.v, o1);
        }
        const size_t off = base + (size_t)jq * 32;
        uint2 u0, u1;
        u0.x = packbf(o0[0] * iv, o0[1] * iv);
        u0.y = packbf(o0[2] * iv, o0[3] * iv);
        u1.x = packbf(o1[0] * iv, o1[1] * iv);
        u1.y = packbf(o1[2] * iv, o1[3] * iv);
        *reinterpret_cast<uint2*>(&OPre[off + 4 * lg])      = u0;
        *reinterpret_cast<uint2*>(&OPre[off + 16 + 4 * lg]) = u1;
    }
}

// ---------------- K3: out = (g .* OPre) @ Wout + bout (gating fused) -------
__device__ __forceinline__ unsigned int gate2(unsigned int o2, unsigned int g2, bool mk) {
    float a0 = bf2f((ushort)(o2 & 0xffffu)), a1 = bf2f((ushort)(o2 >> 16));
    float g0 = mk ? NEGV : bf2f((ushort)(g2 & 0xffffu));
    float g1 = mk ? NEGV : bf2f((ushort)(g2 >> 16));
    return packbf(a0 * g0, a1 * g1);
}

__global__ __launch_bounds__(256) void k_gemm_out(
    const ushort* __restrict__ OPre, const ushort* __restrict__ Gw,
    const int* __restrict__ mask, const ushort* __restrict__ WoT,
    const float* __restrict__ bout, float* __restrict__ out)
{
    __shared__ __align__(16) ushort As[64][136];
    __shared__ __align__(16) ushort Bs[128][136];
    const int tid = threadIdx.x;
    const int p0 = blockIdx.x * 64;
    #pragma unroll
    for (int it = 0; it < 4; ++it) {
        int idx = it * 256 + tid;
        int r = idx >> 4, c = (idx & 15) * 8;
        int hh = c >> 5, dq = c & 31;
        const int p = p0 + r;
        const size_t go = (size_t)hh * HSTR + (size_t)p * 32 + dq;
        uint4 ov = *reinterpret_cast<const uint4*>(&OPre[go]);
        uint4 gv = *reinterpret_cast<const uint4*>(&Gw[go]);
        const bool mk = (mask[p] == 0);
        uint4 rs;
        rs.x = gate2(ov.x, gv.x, mk);
        rs.y = gate2(ov.y, gv.y, mk);
        rs.z = gate2(ov.z, gv.z, mk);
        rs.w = gate2(ov.w, gv.w, mk);
        *reinterpret_cast<uint4*>(&As[r][c]) = rs;
    }
    #pragma unroll
    for (int it = 0; it < 8; ++it) {
        int idx = it * 256 + tid;
        int r = idx >> 4, c = (idx & 15) * 8;
        *reinterpret_cast<uint4*>(&Bs[r][c]) =
            *reinterpret_cast<const uint4*>(&WoT[(size_t)r * DD + c]);
    }
    __syncthreads();
    const int w = tid >> 6, lane = tid & 63;
    const int wm = w >> 1, wn = w & 1;
    const int lr = lane & 15, lg = lane >> 4;
    const f32x4 zz = {0.f, 0.f, 0.f, 0.f};
    f32x4 acc[2][4];
    #pragma unroll
    for (int m = 0; m < 2; ++m)
        #pragma unroll
        for (int n = 0; n < 4; ++n) acc[m][n] = zz;
    #pragma unroll
    for (int kk = 0; kk < 4; ++kk) {
        bf16x8 a0 = *reinterpret_cast<const bf16x8*>(&As[wm * 32 + lr][kk * 32 + lg * 8]);
        bf16x8 a1 = *reinterpret_cast<const bf16x8*>(&As[wm * 32 + 16 + lr][kk * 32 + lg * 8]);
        #pragma unroll
        for (int n = 0; n < 4; ++n) {
            bf16x8 b = *reinterpret_cast<const bf16x8*>(&Bs[wn * 64 + n * 16 + lr][kk * 32 + lg * 8]);
            acc[0][n] = mfma16(a0, b, acc[0][n]);
            acc[1][n] = mfma16(a1, b, acc[1][n]);
        }
    }
    #pragma unroll
    for (int n = 0; n < 4; ++n) {
        const int c = wn * 64 + n * 16 + lr;
        const float bo = bout[c];
        #pragma unroll
        for (int m = 0; m < 2; ++m) {
            #pragma unroll
            for (int r = 0; r < 4; ++r) {
                const int p = p0 + wm * 32 + m * 16 + lg * 4 + r;
                out[(size_t)p * DD + c] = acc[m][n][r] + bo;
            }
        }
    }
}

extern "C" void kernel_launch(void* const* d_in, const int* in_sizes, int n_in,
                              void* d_out, int out_size, void* d_ws, size_t ws_size,
                              hipStream_t stream) {
    const float* edges = (const float*)d_in[0];
    const int*   mask  = (const int*)d_in[1];
    const float* gamma = (const float*)d_in[2];
    const float* beta  = (const float*)d_in[3];
    const float* Wqkv  = (const float*)d_in[4];
    const float* Wb    = (const float*)d_in[5];
    const float* Wg    = (const float*)d_in[6];
    const float* bg    = (const float*)d_in[7];
    const float* Wout  = (const float*)d_in[8];
    const float* bout  = (const float*)d_in[9];
    float* out = (float*)d_out;

    char* ws = (char*)d_ws;
    ushort* OPre = (ushort*)(ws);                              // 16 MiB (head-blocked)
    ushort* Qw  = (ushort*)(ws + 1u * 16777216u);              // head-blocked
    ushort* Kw  = (ushort*)(ws + 2u * 16777216u);
    ushort* Vw  = (ushort*)(ws + 3u * 16777216u);
    ushort* Gw  = (ushort*)(ws + 4u * 16777216u);
    ushort* Bo16 = (ushort*)(ws + 5u * 16777216u);                     // 512 KiB bf16
    ushort* WT  = (ushort*)(ws + 5u * 16777216u + 524288u);            // 128 KiB
    ushort* WoT = (ushort*)(ws + 5u * 16777216u + 524288u + 131072u);  // 32 KiB

    k_wconv<<<dim3(320), dim3(256), 0, stream>>>(Wqkv, Wg, Wout, WT, WoT);
    k_lnqkvg<<<dim3(1024), dim3(256), 0, stream>>>(edges, gamma, beta, Wb, WT, bg,
                                                   Bo16, Qw, Kw, Vw, Gw);
    k_attn9<<<dim3(1024), dim3(256), 0, stream>>>(Qw, Kw, Vw, Bo16, mask, OPre);
    k_gemm_out<<<dim3(1024), dim3(256), 0, stream>>>(OPre, Gw, mask, WoT, bout, out);
}

// Round 12
// 102.893 us; speedup vs baseline: 1.0588x; 1.0588x over previous
//
#include <hip/hip_runtime.h>
#include <hip/hip_bf16.h>
#include <hip/hip_fp16.h>

// Triangle attention (starting node), b=1, n=256, d=128, H=4, DH=32.
// Round 11: fused LN+qkvg GEMM with (a) bias GEMV via per-wave MFMA
// (deletes 128-iter serial loop), (b) swapped-operand epilogues so lanes
// hold 4 consecutive columns -> dense uint2/float4 stores. Attn unchanged.

#define NP  256
#define DD  128
#define HSTR 2097152   // 65536*32, per-head block stride (elements)

typedef short bf16x8 __attribute__((ext_vector_type(8)));
typedef float f32x4  __attribute__((ext_vector_type(4)));

__device__ __forceinline__ float bf2f(ushort u) {
    union { unsigned int v; float f; } c; c.v = ((unsigned int)u) << 16; return c.f;
}
__device__ __forceinline__ float asf(unsigned int v) {
    union { unsigned int v; float f; } c; c.v = v; return c.f;
}
__device__ __forceinline__ ushort f2bf(float f) {
    union { float f; unsigned int v; } c; c.f = f;
    unsigned int x = c.v;
    return (ushort)((x + 0x7FFFu + ((x >> 16) & 1u)) >> 16);  // RNE
}
__device__ __forceinline__ unsigned int packbf(float a, float b) {
    __hip_bfloat162 t = __float22bfloat162_rn(make_float2(a, b));  // a -> low
    union { __hip_bfloat162 h; unsigned int u; } c; c.h = t; return c.u;
}
__device__ __forceinline__ f32x4 mfma16(bf16x8 a, bf16x8 b, f32x4 c) {
    return __builtin_amdgcn_mfma_f32_16x16x32_bf16(a, b, c, 0, 0, 0);
}

#define NEGV (-3.4028234663852886e38f)
#define SCALE 0.17677669529663687f

// ---------------- K0: W -> bf16 transposed + WbT16 (16x128, zero-padded) ---
__global__ __launch_bounds__(256) void k_wconv(
    const float* __restrict__ Wqkv, const float* __restrict__ Wg,
    const float* __restrict__ Wout, const float* __restrict__ Wb,
    ushort* __restrict__ WT, ushort* __restrict__ WoT,
    ushort* __restrict__ WbT16)
{
    int idx = blockIdx.x * 256 + threadIdx.x;   // grid 328 -> 83968
    if (idx < 65536) {
        int n = idx >> 7, k = idx & 127;
        float v = (n < 384) ? Wqkv[(size_t)k * 384 + n]
                            : Wg[(size_t)k * 128 + (n - 384)];
        WT[idx] = f2bf(v);
    } else if (idx < 81920) {
        int i2 = idx - 65536;
        int c = i2 >> 7, e = i2 & 127;
        WoT[i2] = f2bf(Wout[(size_t)e * 128 + c]);
    } else {
        int i3 = idx - 81920;
        int c = i3 >> 7, e = i3 & 127;
        WbT16[i3] = (c < 4) ? f2bf(Wb[(size_t)e * 4 + c]) : (ushort)0;
    }
}

// ---------------- K1: fused LN + bias-MFMA + x @ [Wqkv|Wg] MFMA GEMM -------
// grid 1024 x 256 thr.
__global__ __launch_bounds__(256) void k_lnqkvg(
    const float* __restrict__ edges, const float* __restrict__ gamma,
    const float* __restrict__ beta,  const ushort* __restrict__ WbT16,
    const ushort* __restrict__ WT,   const float* __restrict__ bg,
    ushort* __restrict__ Bo16,
    ushort* __restrict__ Qo, ushort* __restrict__ Ko,
    ushort* __restrict__ Vo, ushort* __restrict__ Go)
{
    __shared__ __align__(16) ushort As[64][136];
    __shared__ __align__(16) ushort Bs[128][136];
    const int tid = threadIdx.x, w = tid >> 6, lane = tid & 63;
    const int lr = lane & 15, lg = lane >> 4;
    const int wm = w >> 1, wn = w & 1;
    const int p0 = blockIdx.x * 64;
    const f32x4 zz = {0.f, 0.f, 0.f, 0.f};

    // --- LN phase: wave w handles rows w*16..w*16+15 -> bf16 into As ---
    {
        const float g0 = gamma[lane], g1 = gamma[lane + 64];
        const float b0 = beta[lane],  b1 = beta[lane + 64];
        for (int pp = 0; pp < 16; ++pp) {
            const int row = w * 16 + pp;
            const float* ep = edges + (size_t)(p0 + row) * DD;
            float e0 = ep[lane], e1 = ep[lane + 64];
            float s = e0 + e1;
            #pragma unroll
            for (int off = 1; off < 64; off <<= 1) s += __shfl_xor(s, off);
            float mu = s * 0.0078125f;
            float d0 = e0 - mu, d1 = e1 - mu;
            float ss = d0 * d0 + d1 * d1;
            #pragma unroll
            for (int off = 1; off < 64; off <<= 1) ss += __shfl_xor(ss, off);
            float rstd = rsqrtf(ss * 0.0078125f + 1e-5f);
            As[row][lane]      = f2bf(d0 * rstd * g0 + b0);
            As[row][lane + 64] = f2bf(d1 * rstd * g1 + b1);
        }
    }
    // --- bias via MFMA: wave reads ONLY its own 16 rows (no barrier) ---
    {
        f32x4 bacc = zz;
        #pragma unroll
        for (int kk = 0; kk < 4; ++kk) {
            bf16x8 wb = *reinterpret_cast<const bf16x8*>(&WbT16[(size_t)lr * DD + kk * 32 + lg * 8]);
            bf16x8 xf = *reinterpret_cast<const bf16x8*>(&As[w * 16 + lr][kk * 32 + lg * 8]);
            bacc = mfma16(wb, xf, bacc);   // out[c=4lg+r][p=w*16+lr]
        }
        if (lg == 0) {   // c = r < 4 are the valid head columns
            const int p = p0 + w * 16 + lr;
            const int j = p >> 8, k = p & 255;
            const int fn = k >> 4, lgk = (k >> 2) & 3, rr = k & 3;
            const size_t fo = (((size_t)j * 4 + lgk) * 16 + fn) * 4 + rr;
            #pragma unroll
            for (int r = 0; r < 4; ++r)
                Bo16[(size_t)r * 65536 + fo] = f2bf(bacc[r]);
        }
    }

    for (int seg = 0; seg < 4; ++seg) {
        const int n0 = seg * 128;
        __syncthreads();   // seg0: LN done block-wide; seg>0: Bs reads done
        #pragma unroll
        for (int it = 0; it < 8; ++it) {
            int idx = it * 256 + tid;
            int r = idx >> 4, c = (idx & 15) * 8;
            *reinterpret_cast<uint4*>(&Bs[r][c]) =
                *reinterpret_cast<const uint4*>(&WT[(size_t)(n0 + r) * DD + c]);
        }
        __syncthreads();
        f32x4 acc[2][4];
        #pragma unroll
        for (int m = 0; m < 2; ++m)
            #pragma unroll
            for (int n = 0; n < 4; ++n) acc[m][n] = zz;
        #pragma unroll
        for (int kk = 0; kk < 4; ++kk) {
            bf16x8 a0 = *reinterpret_cast<const bf16x8*>(&As[wm * 32 + lr][kk * 32 + lg * 8]);
            bf16x8 a1 = *reinterpret_cast<const bf16x8*>(&As[wm * 32 + 16 + lr][kk * 32 + lg * 8]);
            #pragma unroll
            for (int n = 0; n < 4; ++n) {
                bf16x8 b = *reinterpret_cast<const bf16x8*>(&Bs[wn * 64 + n * 16 + lr][kk * 32 + lg * 8]);
                // swapped: out[cc = wn*64+n*16+4lg+r][p = wm*32+(m*16)+lr]
                acc[0][n] = mfma16(b, a0, acc[0][n]);
                acc[1][n] = mfma16(b, a1, acc[1][n]);
            }
        }
        // epilogue: lane holds 4 consecutive columns of one row -> uint2
        #pragma unroll
        for (int n = 0; n < 4; ++n) {
            const int ccb = wn * 64 + n * 16 + 4 * lg;   // within 128-col segment
            const int hh = (wn * 64 + n * 16) >> 5;
            const int dhb = ccb & 31;
            float4 bg4;
            if (seg == 3) bg4 = *reinterpret_cast<const float4*>(&bg[ccb]);
            #pragma unroll
            for (int m = 0; m < 2; ++m) {
                const int p = p0 + wm * 32 + m * 16 + lr;
                const size_t off = (size_t)hh * HSTR + (size_t)p * 32 + dhb;
                float v0 = acc[m][n][0], v1 = acc[m][n][1];
                float v2 = acc[m][n][2], v3 = acc[m][n][3];
                uint2 st;
                if (seg == 0) {
                    st.x = packbf(v0 * SCALE, v1 * SCALE);
                    st.y = packbf(v2 * SCALE, v3 * SCALE);
                    *reinterpret_cast<uint2*>(&Qo[off]) = st;
                } else if (seg == 1) {
                    st.x = packbf(v0, v1); st.y = packbf(v2, v3);
                    *reinterpret_cast<uint2*>(&Ko[off]) = st;
                } else if (seg == 2) {
                    st.x = packbf(v0, v1); st.y = packbf(v2, v3);
                    *reinterpret_cast<uint2*>(&Vo[off]) = st;
                } else {
                    float s0 = 1.0f / (1.0f + __expf(-(v0 + bg4.x)));
                    float s1 = 1.0f / (1.0f + __expf(-(v1 + bg4.y)));
                    float s2 = 1.0f / (1.0f + __expf(-(v2 + bg4.z)));
                    float s3 = 1.0f / (1.0f + __expf(-(v3 + bg4.w)));
                    st.x = packbf(s0, s1); st.y = packbf(s2, s3);
                    *reinterpret_cast<uint2*>(&Go[off]) = st;
                }
            }
        }
    }
}

// ---------------- K2: attention; lane-local PV fragments -------------------
// grid 1024 (1 (i,h) per block). h=(bid&7)>>1 groups heads per XCD (bias
// slice L2-resident). V^T columns key-permuted so packed P words ARE the
// PV B-fragment (no LDS round-trip, no shuffles). launch_bounds(256,2)
// -> 128 VGPR (no spill); LDS 37.9KB + VGPR 128 allow 4 blocks/CU.
__global__ __launch_bounds__(256, 2) void k_attn9(
    const ushort* __restrict__ Qw, const ushort* __restrict__ Kw,
    const ushort* __restrict__ Vw, const ushort* __restrict__ Bo16,
    const int* __restrict__ mask, ushort* __restrict__ OPre)
{
    __shared__ __align__(16) ushort Ks[256][40];   // K rows: 20.0KB
    __shared__ __align__(16) ushort Vt[32][268];   // V^T (key-permuted): 16.75KB
    const int tid = threadIdx.x, w = tid >> 6, lane = tid & 63;
    const int lr = lane & 15, lg = lane >> 4;
    const int bid = blockIdx.x;
    const int h = (bid & 7) >> 1;
    const int i = ((bid >> 3) << 1) | (bid & 1);
    const int ib = i * NP;
    const size_t base = (size_t)h * HSTR + (size_t)ib * 32;   // + k*32 + dh

    #pragma unroll
    for (int it = 0; it < 4; ++it) {
        int idx = it * 256 + tid;
        int r = idx >> 2, c = (idx & 3) * 8;
        *reinterpret_cast<uint4*>(&Ks[r][c]) =
            *reinterpret_cast<const uint4*>(&Kw[base + (size_t)r * 32 + c]);
    }
    #pragma unroll
    for (int it = 0; it < 8; ++it) {
        int idx = it * 256 + tid;
        int d = idx & 31, k4 = (idx >> 5) * 4;
        int kk4 = (k4 & ~31) | (((k4 >> 2) & 1) << 4) | (((k4 >> 3) & 3) << 2);
        ushort4 v;
        v.x = Vw[base + (size_t)(kk4 + 0) * 32 + d];
        v.y = Vw[base + (size_t)(kk4 + 1) * 32 + d];
        v.z = Vw[base + (size_t)(kk4 + 2) * 32 + d];
        v.w = Vw[base + (size_t)(kk4 + 3) * 32 + d];
        *reinterpret_cast<ushort4*>(&Vt[d][k4]) = v;
    }
    __syncthreads();

    const ushort* bias_h = Bo16 + (size_t)h * 65536;
    const f32x4 zz = {0.f, 0.f, 0.f, 0.f};

    for (int jt = 0; jt < 4; ++jt) {
        const int jb = jt * 64 + w * 16;
        const int jq = jb + lr;             // this lane's softmax row
        bf16x8 q = *reinterpret_cast<const bf16x8*>(&Qw[base + (size_t)jq * 32 + lg * 8]);
        const ushort* bp = bias_h + ((size_t)jq * 4 + lg) * 64;
        f32x4 s[16];
        #pragma unroll
        for (int u = 0; u < 8; ++u) {
            uint4 b4 = *reinterpret_cast<const uint4*>(bp + u * 8);
            f32x4 s0, s1;
            s0[0] = asf(b4.x << 16); s0[1] = asf(b4.x & 0xffff0000u);
            s0[2] = asf(b4.y << 16); s0[3] = asf(b4.y & 0xffff0000u);
            s1[0] = asf(b4.z << 16); s1[1] = asf(b4.z & 0xffff0000u);
            s1[2] = asf(b4.w << 16); s1[3] = asf(b4.w & 0xffff0000u);
            s[2 * u] = s0; s[2 * u + 1] = s1;
        }
        #pragma unroll
        for (int fn = 0; fn < 16; ++fn) {
            bf16x8 a = *reinterpret_cast<const bf16x8*>(&Ks[fn * 16 + lr][lg * 8]);
            s[fn] = mfma16(a, q, s[fn]);    // S^T[k][j]
        }
        float mx = -3.402823466e38f;
        #pragma unroll
        for (int fn = 0; fn < 16; ++fn) {
            float m01 = fmaxf(s[fn][0], s[fn][1]);
            float m23 = fmaxf(s[fn][2], s[fn][3]);
            mx = fmaxf(mx, fmaxf(m01, m23));
        }
        mx = fmaxf(mx, __shfl_xor(mx, 16));
        mx = fmaxf(mx, __shfl_xor(mx, 32));
        float sum = 0.f;
        #pragma unroll
        for (int fn = 0; fn < 16; ++fn) {
            #pragma unroll
            for (int r = 0; r < 4; ++r) {
                float e = __expf(s[fn][r] - mx);
                s[fn][r] = e; sum += e;
            }
        }
        sum += __shfl_xor(sum, 16);
        sum += __shfl_xor(sum, 32);
        const bool masked = (mask[ib + jq] == 0);
        const float iv = masked ? 1.0f : (1.0f / sum);

        f32x4 o0 = zz, o1 = zz;
        #pragma unroll
        for (int m = 0; m < 8; ++m) {
            union { unsigned int u[4]; bf16x8 v; } pa;
            pa.u[0] = masked ? 0x3B803B80u : packbf(s[2 * m][0], s[2 * m][1]);
            pa.u[1] = masked ? 0x3B803B80u : packbf(s[2 * m][2], s[2 * m][3]);
            pa.u[2] = masked ? 0x3B803B80u : packbf(s[2 * m + 1][0], s[2 * m + 1][1]);
            pa.u[3] = masked ? 0x3B803B80u : packbf(s[2 * m + 1][2], s[2 * m + 1][3]);
            bf16x8 v0 = *reinterpret_cast<const bf16x8*>(&Vt[lr][m * 32 + lg * 8]);
            bf16x8 v1 = *reinterpret_cast<const bf16x8*>(&Vt[16 + lr][m * 32 + lg * 8]);
            o0 = mfma16(v0, pa.v, o0);
            o1 = mfma16(v1, pa.v, o1);
        }
        const size_t off = base + (size_t)jq * 32;
        uint2 u0, u1;
        u0.x = packbf(o0[0] * iv, o0[1] * iv);
        u0.y = packbf(o0[2] * iv, o0[3] * iv);
        u1.x = packbf(o1[0] * iv, o1[1] * iv);
        u1.y = packbf(o1[2] * iv, o1[3] * iv);
        *reinterpret_cast<uint2*>(&OPre[off + 4 * lg])      = u0;
        *reinterpret_cast<uint2*>(&OPre[off + 16 + 4 * lg]) = u1;
    }
}

// ---------------- K3: out = (g .* OPre) @ Wout + bout (gating fused) -------
__device__ __forceinline__ unsigned int gate2(unsigned int o2, unsigned int g2, bool mk) {
    float a0 = bf2f((ushort)(o2 & 0xffffu)), a1 = bf2f((ushort)(o2 >> 16));
    float g0 = mk ? NEGV : bf2f((ushort)(g2 & 0xffffu));
    float g1 = mk ? NEGV : bf2f((ushort)(g2 >> 16));
    return packbf(a0 * g0, a1 * g1);
}

__global__ __launch_bounds__(256) void k_gemm_out(
    const ushort* __restrict__ OPre, const ushort* __restrict__ Gw,
    const int* __restrict__ mask, const ushort* __restrict__ WoT,
    const float* __restrict__ bout, float* __restrict__ out)
{
    __shared__ __align__(16) ushort As[64][136];
    __shared__ __align__(16) ushort Bs[128][136];
    const int tid = threadIdx.x;
    const int p0 = blockIdx.x * 64;
    #pragma unroll
    for (int it = 0; it < 4; ++it) {
        int idx = it * 256 + tid;
        int r = idx >> 4, c = (idx & 15) * 8;
        int hh = c >> 5, dq = c & 31;
        const int p = p0 + r;
        const size_t go = (size_t)hh * HSTR + (size_t)p * 32 + dq;
        uint4 ov = *reinterpret_cast<const uint4*>(&OPre[go]);
        uint4 gv = *reinterpret_cast<const uint4*>(&Gw[go]);
        const bool mk = (mask[p] == 0);
        uint4 rs;
        rs.x = gate2(ov.x, gv.x, mk);
        rs.y = gate2(ov.y, gv.y, mk);
        rs.z = gate2(ov.z, gv.z, mk);
        rs.w = gate2(ov.w, gv.w, mk);
        *reinterpret_cast<uint4*>(&As[r][c]) = rs;
    }
    #pragma unroll
    for (int it = 0; it < 8; ++it) {
        int idx = it * 256 + tid;
        int r = idx >> 4, c = (idx & 15) * 8;
        *reinterpret_cast<uint4*>(&Bs[r][c]) =
            *reinterpret_cast<const uint4*>(&WoT[(size_t)r * DD + c]);
    }
    __syncthreads();
    const int w = tid >> 6, lane = tid & 63;
    const int wm = w >> 1, wn = w & 1;
    const int lr = lane & 15, lg = lane >> 4;
    const f32x4 zz = {0.f, 0.f, 0.f, 0.f};
    f32x4 acc[2][4];
    #pragma unroll
    for (int m = 0; m < 2; ++m)
        #pragma unroll
        for (int n = 0; n < 4; ++n) acc[m][n] = zz;
    #pragma unroll
    for (int kk = 0; kk < 4; ++kk) {
        bf16x8 a0 = *reinterpret_cast<const bf16x8*>(&As[wm * 32 + lr][kk * 32 + lg * 8]);
        bf16x8 a1 = *reinterpret_cast<const bf16x8*>(&As[wm * 32 + 16 + lr][kk * 32 + lg * 8]);
        #pragma unroll
        for (int n = 0; n < 4; ++n) {
            bf16x8 b = *reinterpret_cast<const bf16x8*>(&Bs[wn * 64 + n * 16 + lr][kk * 32 + lg * 8]);
            // swapped: out[c = wn*64+n*16+4lg+r][p = wm*32+(m*16)+lr]
            acc[0][n] = mfma16(b, a0, acc[0][n]);
            acc[1][n] = mfma16(b, a1, acc[1][n]);
        }
    }
    #pragma unroll
    for (int n = 0; n < 4; ++n) {
        const int cb = wn * 64 + n * 16 + 4 * lg;
        const float4 bo4 = *reinterpret_cast<const float4*>(&bout[cb]);
        #pragma unroll
        for (int m = 0; m < 2; ++m) {
            const int p = p0 + wm * 32 + m * 16 + lr;
            float4 st;
            st.x = acc[m][n][0] + bo4.x;
            st.y = acc[m][n][1] + bo4.y;
            st.z = acc[m][n][2] + bo4.z;
            st.w = acc[m][n][3] + bo4.w;
            *reinterpret_cast<float4*>(&out[(size_t)p * DD + cb]) = st;
        }
    }
}

extern "C" void kernel_launch(void* const* d_in, const int* in_sizes, int n_in,
                              void* d_out, int out_size, void* d_ws, size_t ws_size,
                              hipStream_t stream) {
    const float* edges = (const float*)d_in[0];
    const int*   mask  = (const int*)d_in[1];
    const float* gamma = (const float*)d_in[2];
    const float* beta  = (const float*)d_in[3];
    const float* Wqkv  = (const float*)d_in[4];
    const float* Wb    = (const float*)d_in[5];
    const float* Wg    = (const float*)d_in[6];
    const float* bg    = (const float*)d_in[7];
    const float* Wout  = (const float*)d_in[8];
    const float* bout  = (const float*)d_in[9];
    float* out = (float*)d_out;

    char* ws = (char*)d_ws;
    ushort* OPre = (ushort*)(ws);                              // 16 MiB (head-blocked)
    ushort* Qw  = (ushort*)(ws + 1u * 16777216u);              // head-blocked
    ushort* Kw  = (ushort*)(ws + 2u * 16777216u);
    ushort* Vw  = (ushort*)(ws + 3u * 16777216u);
    ushort* Gw  = (ushort*)(ws + 4u * 16777216u);
    ushort* Bo16 = (ushort*)(ws + 5u * 16777216u);                     // 512 KiB bf16
    ushort* WT  = (ushort*)(ws + 5u * 16777216u + 524288u);            // 128 KiB
    ushort* WoT = (ushort*)(ws + 5u * 16777216u + 524288u + 131072u);  // 32 KiB
    ushort* WbT16 = (ushort*)(ws + 5u * 16777216u + 524288u + 131072u + 32768u); // 4 KiB

    k_wconv<<<dim3(328), dim3(256), 0, stream>>>(Wqkv, Wg, Wout, Wb, WT, WoT, WbT16);
    k_lnqkvg<<<dim3(1024), dim3(256), 0, stream>>>(edges, gamma, beta, WbT16, WT, bg,
                                                   Bo16, Qw, Kw, Vw, Gw);
    k_attn9<<<dim3(1024), dim3(256), 0, stream>>>(Qw, Kw, Vw, Bo16, mask, OPre);
    k_gemm_out<<<dim3(1024), dim3(256), 0, stream>>>(OPre, Gw, mask, WoT, bout, out);
}

// Round 13
// 92.100 us; speedup vs baseline: 1.1829x; 1.1172x over previous
//
#include <hip/hip_runtime.h>
#include <hip/hip_bf16.h>
#include <hip/hip_fp16.h>

// Triangle attention (starting node), b=1, n=256, d=128, H=4, DH=32.
// Round 12: lane-parallel LN (8 independent float4 loads/lane, 4-shuffle
// reduce, b128 LDS writes) replaces the 16-serial-HBM-load LN loop in the
// fused kernel. Everything else unchanged from round 11.

#define NP  256
#define DD  128
#define HSTR 2097152   // 65536*32, per-head block stride (elements)

typedef short bf16x8 __attribute__((ext_vector_type(8)));
typedef float f32x4  __attribute__((ext_vector_type(4)));

__device__ __forceinline__ float bf2f(ushort u) {
    union { unsigned int v; float f; } c; c.v = ((unsigned int)u) << 16; return c.f;
}
__device__ __forceinline__ float asf(unsigned int v) {
    union { unsigned int v; float f; } c; c.v = v; return c.f;
}
__device__ __forceinline__ ushort f2bf(float f) {
    union { float f; unsigned int v; } c; c.f = f;
    unsigned int x = c.v;
    return (ushort)((x + 0x7FFFu + ((x >> 16) & 1u)) >> 16);  // RNE
}
__device__ __forceinline__ unsigned int packbf(float a, float b) {
    __hip_bfloat162 t = __float22bfloat162_rn(make_float2(a, b));  // a -> low
    union { __hip_bfloat162 h; unsigned int u; } c; c.h = t; return c.u;
}
__device__ __forceinline__ f32x4 mfma16(bf16x8 a, bf16x8 b, f32x4 c) {
    return __builtin_amdgcn_mfma_f32_16x16x32_bf16(a, b, c, 0, 0, 0);
}

#define NEGV (-3.4028234663852886e38f)
#define SCALE 0.17677669529663687f

// ---------------- K0: W -> bf16 transposed + WbT16 (16x128, zero-padded) ---
__global__ __launch_bounds__(256) void k_wconv(
    const float* __restrict__ Wqkv, const float* __restrict__ Wg,
    const float* __restrict__ Wout, const float* __restrict__ Wb,
    ushort* __restrict__ WT, ushort* __restrict__ WoT,
    ushort* __restrict__ WbT16)
{
    int idx = blockIdx.x * 256 + threadIdx.x;   // grid 328 -> 83968
    if (idx < 65536) {
        int n = idx >> 7, k = idx & 127;
        float v = (n < 384) ? Wqkv[(size_t)k * 384 + n]
                            : Wg[(size_t)k * 128 + (n - 384)];
        WT[idx] = f2bf(v);
    } else if (idx < 81920) {
        int i2 = idx - 65536;
        int c = i2 >> 7, e = i2 & 127;
        WoT[i2] = f2bf(Wout[(size_t)e * 128 + c]);
    } else {
        int i3 = idx - 81920;
        int c = i3 >> 7, e = i3 & 127;
        WbT16[i3] = (c < 4) ? f2bf(Wb[(size_t)e * 4 + c]) : (ushort)0;
    }
}

// ---------------- K1: fused LN + bias-MFMA + x @ [Wqkv|Wg] MFMA GEMM -------
// grid 1024 x 256 thr. LN is lane-parallel: lane owns (row=w*16+(lane&15),
// cols (lane>>4)*32..+31); 8 independent float4 loads, 4-shuffle reduce.
__global__ __launch_bounds__(256) void k_lnqkvg(
    const float* __restrict__ edges, const float* __restrict__ gamma,
    const float* __restrict__ beta,  const ushort* __restrict__ WbT16,
    const ushort* __restrict__ WT,   const float* __restrict__ bg,
    ushort* __restrict__ Bo16,
    ushort* __restrict__ Qo, ushort* __restrict__ Ko,
    ushort* __restrict__ Vo, ushort* __restrict__ Go)
{
    __shared__ __align__(16) ushort As[64][136];
    __shared__ __align__(16) ushort Bs[128][136];
    const int tid = threadIdx.x, w = tid >> 6, lane = tid & 63;
    const int lr = lane & 15, lg = lane >> 4;
    const int wm = w >> 1, wn = w & 1;
    const int p0 = blockIdx.x * 64;
    const f32x4 zz = {0.f, 0.f, 0.f, 0.f};

    // --- LN phase (loop-free): row = w*16+lr, part = lg ---
    {
        const int row = w * 16 + lr;
        const int part = lg;
        const float* ep = edges + (size_t)(p0 + row) * DD + part * 32;
        float4 xv[8];
        #pragma unroll
        for (int t = 0; t < 8; ++t)
            xv[t] = *reinterpret_cast<const float4*>(ep + t * 4);
        float s = 0.f, ss = 0.f;
        #pragma unroll
        for (int t = 0; t < 8; ++t) {
            s  += (xv[t].x + xv[t].y) + (xv[t].z + xv[t].w);
            ss += (xv[t].x * xv[t].x + xv[t].y * xv[t].y)
                + (xv[t].z * xv[t].z + xv[t].w * xv[t].w);
        }
        s  += __shfl_xor(s, 16);  s  += __shfl_xor(s, 32);
        ss += __shfl_xor(ss, 16); ss += __shfl_xor(ss, 32);
        const float mu = s * 0.0078125f;
        const float var = ss * 0.0078125f - mu * mu;
        const float rstd = rsqrtf(var + 1e-5f);
        const float* gp = gamma + part * 32;
        const float* bp = beta + part * 32;
        #pragma unroll
        for (int u = 0; u < 4; ++u) {
            float4 a = xv[2 * u], b = xv[2 * u + 1];
            float4 ga = *reinterpret_cast<const float4*>(gp + u * 8);
            float4 gb = *reinterpret_cast<const float4*>(gp + u * 8 + 4);
            float4 ba = *reinterpret_cast<const float4*>(bp + u * 8);
            float4 bb = *reinterpret_cast<const float4*>(bp + u * 8 + 4);
            // val = (x-mu)*rstd*g + b  ==  x*cg + (b - mu*cg)
            float cg;
            uint4 st;
            float v0, v1;
            cg = rstd * ga.x; v0 = a.x * cg + (ba.x - mu * cg);
            cg = rstd * ga.y; v1 = a.y * cg + (ba.y - mu * cg);
            st.x = packbf(v0, v1);
            cg = rstd * ga.z; v0 = a.z * cg + (ba.z - mu * cg);
            cg = rstd * ga.w; v1 = a.w * cg + (ba.w - mu * cg);
            st.y = packbf(v0, v1);
            cg = rstd * gb.x; v0 = b.x * cg + (bb.x - mu * cg);
            cg = rstd * gb.y; v1 = b.y * cg + (bb.y - mu * cg);
            st.z = packbf(v0, v1);
            cg = rstd * gb.z; v0 = b.z * cg + (bb.z - mu * cg);
            cg = rstd * gb.w; v1 = b.w * cg + (bb.w - mu * cg);
            st.w = packbf(v0, v1);
            *reinterpret_cast<uint4*>(&As[row][part * 32 + u * 8]) = st;
        }
    }
    // --- bias via MFMA: wave reads ONLY its own 16 rows (no barrier) ---
    {
        f32x4 bacc = zz;
        #pragma unroll
        for (int kk = 0; kk < 4; ++kk) {
            bf16x8 wb = *reinterpret_cast<const bf16x8*>(&WbT16[(size_t)lr * DD + kk * 32 + lg * 8]);
            bf16x8 xf = *reinterpret_cast<const bf16x8*>(&As[w * 16 + lr][kk * 32 + lg * 8]);
            bacc = mfma16(wb, xf, bacc);   // out[c=4lg+r][p=w*16+lr]
        }
        if (lg == 0) {   // c = r < 4 are the valid head columns
            const int p = p0 + w * 16 + lr;
            const int j = p >> 8, k = p & 255;
            const int fn = k >> 4, lgk = (k >> 2) & 3, rr = k & 3;
            const size_t fo = (((size_t)j * 4 + lgk) * 16 + fn) * 4 + rr;
            #pragma unroll
            for (int r = 0; r < 4; ++r)
                Bo16[(size_t)r * 65536 + fo] = f2bf(bacc[r]);
        }
    }

    for (int seg = 0; seg < 4; ++seg) {
        const int n0 = seg * 128;
        __syncthreads();   // seg0: LN done block-wide; seg>0: Bs reads done
        #pragma unroll
        for (int it = 0; it < 8; ++it) {
            int idx = it * 256 + tid;
            int r = idx >> 4, c = (idx & 15) * 8;
            *reinterpret_cast<uint4*>(&Bs[r][c]) =
                *reinterpret_cast<const uint4*>(&WT[(size_t)(n0 + r) * DD + c]);
        }
        __syncthreads();
        f32x4 acc[2][4];
        #pragma unroll
        for (int m = 0; m < 2; ++m)
            #pragma unroll
            for (int n = 0; n < 4; ++n) acc[m][n] = zz;
        #pragma unroll
        for (int kk = 0; kk < 4; ++kk) {
            bf16x8 a0 = *reinterpret_cast<const bf16x8*>(&As[wm * 32 + lr][kk * 32 + lg * 8]);
            bf16x8 a1 = *reinterpret_cast<const bf16x8*>(&As[wm * 32 + 16 + lr][kk * 32 + lg * 8]);
            #pragma unroll
            for (int n = 0; n < 4; ++n) {
                bf16x8 b = *reinterpret_cast<const bf16x8*>(&Bs[wn * 64 + n * 16 + lr][kk * 32 + lg * 8]);
                // swapped: out[cc = wn*64+n*16+4lg+r][p = wm*32+(m*16)+lr]
                acc[0][n] = mfma16(b, a0, acc[0][n]);
                acc[1][n] = mfma16(b, a1, acc[1][n]);
            }
        }
        // epilogue: lane holds 4 consecutive columns of one row -> uint2
        #pragma unroll
        for (int n = 0; n < 4; ++n) {
            const int ccb = wn * 64 + n * 16 + 4 * lg;   // within 128-col segment
            const int hh = (wn * 64 + n * 16) >> 5;
            const int dhb = ccb & 31;
            float4 bg4;
            if (seg == 3) bg4 = *reinterpret_cast<const float4*>(&bg[ccb]);
            #pragma unroll
            for (int m = 0; m < 2; ++m) {
                const int p = p0 + wm * 32 + m * 16 + lr;
                const size_t off = (size_t)hh * HSTR + (size_t)p * 32 + dhb;
                float v0 = acc[m][n][0], v1 = acc[m][n][1];
                float v2 = acc[m][n][2], v3 = acc[m][n][3];
                uint2 st;
                if (seg == 0) {
                    st.x = packbf(v0 * SCALE, v1 * SCALE);
                    st.y = packbf(v2 * SCALE, v3 * SCALE);
                    *reinterpret_cast<uint2*>(&Qo[off]) = st;
                } else if (seg == 1) {
                    st.x = packbf(v0, v1); st.y = packbf(v2, v3);
                    *reinterpret_cast<uint2*>(&Ko[off]) = st;
                } else if (seg == 2) {
                    st.x = packbf(v0, v1); st.y = packbf(v2, v3);
                    *reinterpret_cast<uint2*>(&Vo[off]) = st;
                } else {
                    float s0 = 1.0f / (1.0f + __expf(-(v0 + bg4.x)));
                    float s1 = 1.0f / (1.0f + __expf(-(v1 + bg4.y)));
                    float s2 = 1.0f / (1.0f + __expf(-(v2 + bg4.z)));
                    float s3 = 1.0f / (1.0f + __expf(-(v3 + bg4.w)));
                    st.x = packbf(s0, s1); st.y = packbf(s2, s3);
                    *reinterpret_cast<uint2*>(&Go[off]) = st;
                }
            }
        }
    }
}

// ---------------- K2: attention; lane-local PV fragments -------------------
// grid 1024 (1 (i,h) per block). h=(bid&7)>>1 groups heads per XCD (bias
// slice L2-resident). V^T columns key-permuted so packed P words ARE the
// PV B-fragment (no LDS round-trip, no shuffles). launch_bounds(256,2)
// -> 128 VGPR (no spill); LDS 37.9KB + VGPR 128 allow 4 blocks/CU.
__global__ __launch_bounds__(256, 2) void k_attn9(
    const ushort* __restrict__ Qw, const ushort* __restrict__ Kw,
    const ushort* __restrict__ Vw, const ushort* __restrict__ Bo16,
    const int* __restrict__ mask, ushort* __restrict__ OPre)
{
    __shared__ __align__(16) ushort Ks[256][40];   // K rows: 20.0KB
    __shared__ __align__(16) ushort Vt[32][268];   // V^T (key-permuted): 16.75KB
    const int tid = threadIdx.x, w = tid >> 6, lane = tid & 63;
    const int lr = lane & 15, lg = lane >> 4;
    const int bid = blockIdx.x;
    const int h = (bid & 7) >> 1;
    const int i = ((bid >> 3) << 1) | (bid & 1);
    const int ib = i * NP;
    const size_t base = (size_t)h * HSTR + (size_t)ib * 32;   // + k*32 + dh

    #pragma unroll
    for (int it = 0; it < 4; ++it) {
        int idx = it * 256 + tid;
        int r = idx >> 2, c = (idx & 3) * 8;
        *reinterpret_cast<uint4*>(&Ks[r][c]) =
            *reinterpret_cast<const uint4*>(&Kw[base + (size_t)r * 32 + c]);
    }
    #pragma unroll
    for (int it = 0; it < 8; ++it) {
        int idx = it * 256 + tid;
        int d = idx & 31, k4 = (idx >> 5) * 4;
        int kk4 = (k4 & ~31) | (((k4 >> 2) & 1) << 4) | (((k4 >> 3) & 3) << 2);
        ushort4 v;
        v.x = Vw[base + (size_t)(kk4 + 0) * 32 + d];
        v.y = Vw[base + (size_t)(kk4 + 1) * 32 + d];
        v.z = Vw[base + (size_t)(kk4 + 2) * 32 + d];
        v.w = Vw[base + (size_t)(kk4 + 3) * 32 + d];
        *reinterpret_cast<ushort4*>(&Vt[d][k4]) = v;
    }
    __syncthreads();

    const ushort* bias_h = Bo16 + (size_t)h * 65536;
    const f32x4 zz = {0.f, 0.f, 0.f, 0.f};

    for (int jt = 0; jt < 4; ++jt) {
        const int jb = jt * 64 + w * 16;
        const int jq = jb + lr;             // this lane's softmax row
        bf16x8 q = *reinterpret_cast<const bf16x8*>(&Qw[base + (size_t)jq * 32 + lg * 8]);
        const ushort* bp = bias_h + ((size_t)jq * 4 + lg) * 64;
        f32x4 s[16];
        #pragma unroll
        for (int u = 0; u < 8; ++u) {
            uint4 b4 = *reinterpret_cast<const uint4*>(bp + u * 8);
            f32x4 s0, s1;
            s0[0] = asf(b4.x << 16); s0[1] = asf(b4.x & 0xffff0000u);
            s0[2] = asf(b4.y << 16); s0[3] = asf(b4.y & 0xffff0000u);
            s1[0] = asf(b4.z << 16); s1[1] = asf(b4.z & 0xffff0000u);
            s1[2] = asf(b4.w << 16); s1[3] = asf(b4.w & 0xffff0000u);
            s[2 * u] = s0; s[2 * u + 1] = s1;
        }
        #pragma unroll
        for (int fn = 0; fn < 16; ++fn) {
            bf16x8 a = *reinterpret_cast<const bf16x8*>(&Ks[fn * 16 + lr][lg * 8]);
            s[fn] = mfma16(a, q, s[fn]);    // S^T[k][j]
        }
        float mx = -3.402823466e38f;
        #pragma unroll
        for (int fn = 0; fn < 16; ++fn) {
            float m01 = fmaxf(s[fn][0], s[fn][1]);
            float m23 = fmaxf(s[fn][2], s[fn][3]);
            mx = fmaxf(mx, fmaxf(m01, m23));
        }
        mx = fmaxf(mx, __shfl_xor(mx, 16));
        mx = fmaxf(mx, __shfl_xor(mx, 32));
        float sum = 0.f;
        #pragma unroll
        for (int fn = 0; fn < 16; ++fn) {
            #pragma unroll
            for (int r = 0; r < 4; ++r) {
                float e = __expf(s[fn][r] - mx);
                s[fn][r] = e; sum += e;
            }
        }
        sum += __shfl_xor(sum, 16);
        sum += __shfl_xor(sum, 32);
        const bool masked = (mask[ib + jq] == 0);
        const float iv = masked ? 1.0f : (1.0f / sum);

        f32x4 o0 = zz, o1 = zz;
        #pragma unroll
        for (int m = 0; m < 8; ++m) {
            union { unsigned int u[4]; bf16x8 v; } pa;
            pa.u[0] = masked ? 0x3B803B80u : packbf(s[2 * m][0], s[2 * m][1]);
            pa.u[1] = masked ? 0x3B803B80u : packbf(s[2 * m][2], s[2 * m][3]);
            pa.u[2] = masked ? 0x3B803B80u : packbf(s[2 * m + 1][0], s[2 * m + 1][1]);
            pa.u[3] = masked ? 0x3B803B80u : packbf(s[2 * m + 1][2], s[2 * m + 1][3]);
            bf16x8 v0 = *reinterpret_cast<const bf16x8*>(&Vt[lr][m * 32 + lg * 8]);
            bf16x8 v1 = *reinterpret_cast<const bf16x8*>(&Vt[16 + lr][m * 32 + lg * 8]);
            o0 = mfma16(v0, pa.v, o0);
            o1 = mfma16(v1, pa.v, o1);
        }
        const size_t off = base + (size_t)jq * 32;
        uint2 u0, u1;
        u0.x = packbf(o0[0] * iv, o0[1] * iv);
        u0.y = packbf(o0[2] * iv, o0[3] * iv);
        u1.x = packbf(o1[0] * iv, o1[1] * iv);
        u1.y = packbf(o1[2] * iv, o1[3] * iv);
        *reinterpret_cast<uint2*>(&OPre[off + 4 * lg])      = u0;
        *reinterpret_cast<uint2*>(&OPre[off + 16 + 4 * lg]) = u1;
    }
}

// ---------------- K3: out = (g .* OPre) @ Wout + bout (gating fused) -------
__device__ __forceinline__ unsigned int gate2(unsigned int o2, unsigned int g2, bool mk) {
    float a0 = bf2f((ushort)(o2 & 0xffffu)), a1 = bf2f((ushort)(o2 >> 16));
    float g0 = mk ? NEGV : bf2f((ushort)(g2 & 0xffffu));
    float g1 = mk ? NEGV : bf2f((ushort)(g2 >> 16));
    return packbf(a0 * g0, a1 * g1);
}

__global__ __launch_bounds__(256) void k_gemm_out(
    const ushort* __restrict__ OPre, const ushort* __restrict__ Gw,
    const int* __restrict__ mask, const ushort* __restrict__ WoT,
    const float* __restrict__ bout, float* __restrict__ out)
{
    __shared__ __align__(16) ushort As[64][136];
    __shared__ __align__(16) ushort Bs[128][136];
    const int tid = threadIdx.x;
    const int p0 = blockIdx.x * 64;
    #pragma unroll
    for (int it = 0; it < 4; ++it) {
        int idx = it * 256 + tid;
        int r = idx >> 4, c = (idx & 15) * 8;
        int hh = c >> 5, dq = c & 31;
        const int p = p0 + r;
        const size_t go = (size_t)hh * HSTR + (size_t)p * 32 + dq;
        uint4 ov = *reinterpret_cast<const uint4*>(&OPre[go]);
        uint4 gv = *reinterpret_cast<const uint4*>(&Gw[go]);
        const bool mk = (mask[p] == 0);
        uint4 rs;
        rs.x = gate2(ov.x, gv.x, mk);
        rs.y = gate2(ov.y, gv.y, mk);
        rs.z = gate2(ov.z, gv.z, mk);
        rs.w = gate2(ov.w, gv.w, mk);
        *reinterpret_cast<uint4*>(&As[r][c]) = rs;
    }
    #pragma unroll
    for (int it = 0; it < 8; ++it) {
        int idx = it * 256 + tid;
        int r = idx >> 4, c = (idx & 15) * 8;
        *reinterpret_cast<uint4*>(&Bs[r][c]) =
            *reinterpret_cast<const uint4*>(&WoT[(size_t)r * DD + c]);
    }
    __syncthreads();
    const int w = tid >> 6, lane = tid & 63;
    const int wm = w >> 1, wn = w & 1;
    const int lr = lane & 15, lg = lane >> 4;
    const f32x4 zz = {0.f, 0.f, 0.f, 0.f};
    f32x4 acc[2][4];
    #pragma unroll
    for (int m = 0; m < 2; ++m)
        #pragma unroll
        for (int n = 0; n < 4; ++n) acc[m][n] = zz;
    #pragma unroll
    for (int kk = 0; kk < 4; ++kk) {
        bf16x8 a0 = *reinterpret_cast<const bf16x8*>(&As[wm * 32 + lr][kk * 32 + lg * 8]);
        bf16x8 a1 = *reinterpret_cast<const bf16x8*>(&As[wm * 32 + 16 + lr][kk * 32 + lg * 8]);
        #pragma unroll
        for (int n = 0; n < 4; ++n) {
            bf16x8 b = *reinterpret_cast<const bf16x8*>(&Bs[wn * 64 + n * 16 + lr][kk * 32 + lg * 8]);
            // swapped: out[c = wn*64+n*16+4lg+r][p = wm*32+(m*16)+lr]
            acc[0][n] = mfma16(b, a0, acc[0][n]);
            acc[1][n] = mfma16(b, a1, acc[1][n]);
        }
    }
    #pragma unroll
    for (int n = 0; n < 4; ++n) {
        const int cb = wn * 64 + n * 16 + 4 * lg;
        const float4 bo4 = *reinterpret_cast<const float4*>(&bout[cb]);
        #pragma unroll
        for (int m = 0; m < 2; ++m) {
            const int p = p0 + wm * 32 + m * 16 + lr;
            float4 st;
            st.x = acc[m][n][0] + bo4.x;
            st.y = acc[m][n][1] + bo4.y;
            st.z = acc[m][n][2] + bo4.z;
            st.w = acc[m][n][3] + bo4.w;
            *reinterpret_cast<float4*>(&out[(size_t)p * DD + cb]) = st;
        }
    }
}

extern "C" void kernel_launch(void* const* d_in, const int* in_sizes, int n_in,
                              void* d_out, int out_size, void* d_ws, size_t ws_size,
                              hipStream_t stream) {
    const float* edges = (const float*)d_in[0];
    const int*   mask  = (const int*)d_in[1];
    const float* gamma = (const float*)d_in[2];
    const float* beta  = (const float*)d_in[3];
    const float* Wqkv  = (const float*)d_in[4];
    const float* Wb    = (const float*)d_in[5];
    const float* Wg    = (const float*)d_in[6];
    const float* bg    = (const float*)d_in[7];
    const float* Wout  = (const float*)d_in[8];
    const float* bout  = (const float*)d_in[9];
    float* out = (float*)d_out;

    char* ws = (char*)d_ws;
    ushort* OPre = (ushort*)(ws);                              // 16 MiB (head-blocked)
    ushort* Qw  = (ushort*)(ws + 1u * 16777216u);              // head-blocked
    ushort* Kw  = (ushort*)(ws + 2u * 16777216u);
    ushort* Vw  = (ushort*)(ws + 3u * 16777216u);
    ushort* Gw  = (ushort*)(ws + 4u * 16777216u);
    ushort* Bo16 = (ushort*)(ws + 5u * 16777216u);                     // 512 KiB bf16
    ushort* WT  = (ushort*)(ws + 5u * 16777216u + 524288u);            // 128 KiB
    ushort* WoT = (ushort*)(ws + 5u * 16777216u + 524288u + 131072u);  // 32 KiB
    ushort* WbT16 = (ushort*)(ws + 5u * 16777216u + 524288u + 131072u + 32768u); // 4 KiB

    k_wconv<<<dim3(328), dim3(256), 0, stream>>>(Wqkv, Wg, Wout, Wb, WT, WoT, WbT16);
    k_lnqkvg<<<dim3(1024), dim3(256), 0, stream>>>(edges, gamma, beta, WbT16, WT, bg,
                                                   Bo16, Qw, Kw, Vw, Gw);
    k_attn9<<<dim3(1024), dim3(256), 0, stream>>>(Qw, Kw, Vw, Bo16, mask, OPre);
    k_gemm_out<<<dim3(1024), dim3(256), 0, stream>>>(OPre, Gw, mask, WoT, bout, out);
}

// Round 15
// 87.829 us; speedup vs baseline: 1.2405x; 1.0486x over previous
//
#include <hip/hip_runtime.h>
#include <hip/hip_bf16.h>
#include <hip/hip_fp16.h>

// Triangle attention (starting node), b=1, n=256, d=128, H=4, DH=32.
// Round 14: round-13 design with the grid bug fixed — k_attn10 handles ONE
// (i,h) per block, so grid must be 1024 (was 512: i>=128 never computed).
// 512-thread attn blocks (8 waves, 2 j-tiles/wave), gating fused in attn,
// gemm_out staging is a plain copy.

#define NP  256
#define DD  128
#define HSTR 2097152   // 65536*32, per-head block stride (elements)

typedef short bf16x8 __attribute__((ext_vector_type(8)));
typedef float f32x4  __attribute__((ext_vector_type(4)));

__device__ __forceinline__ float bf2f(ushort u) {
    union { unsigned int v; float f; } c; c.v = ((unsigned int)u) << 16; return c.f;
}
__device__ __forceinline__ float asf(unsigned int v) {
    union { unsigned int v; float f; } c; c.v = v; return c.f;
}
__device__ __forceinline__ ushort f2bf(float f) {
    union { float f; unsigned int v; } c; c.f = f;
    unsigned int x = c.v;
    return (ushort)((x + 0x7FFFu + ((x >> 16) & 1u)) >> 16);  // RNE
}
__device__ __forceinline__ unsigned int packbf(float a, float b) {
    __hip_bfloat162 t = __float22bfloat162_rn(make_float2(a, b));  // a -> low
    union { __hip_bfloat162 h; unsigned int u; } c; c.h = t; return c.u;
}
__device__ __forceinline__ f32x4 mfma16(bf16x8 a, bf16x8 b, f32x4 c) {
    return __builtin_amdgcn_mfma_f32_16x16x32_bf16(a, b, c, 0, 0, 0);
}

#define NEGV (-3.4028234663852886e38f)
#define SCALE 0.17677669529663687f

// ---------------- K0: W -> bf16 transposed + WbT16 (16x128, zero-padded) ---
__global__ __launch_bounds__(256) void k_wconv(
    const float* __restrict__ Wqkv, const float* __restrict__ Wg,
    const float* __restrict__ Wout, const float* __restrict__ Wb,
    ushort* __restrict__ WT, ushort* __restrict__ WoT,
    ushort* __restrict__ WbT16)
{
    int idx = blockIdx.x * 256 + threadIdx.x;   // grid 328 -> 83968
    if (idx < 65536) {
        int n = idx >> 7, k = idx & 127;
        float v = (n < 384) ? Wqkv[(size_t)k * 384 + n]
                            : Wg[(size_t)k * 128 + (n - 384)];
        WT[idx] = f2bf(v);
    } else if (idx < 81920) {
        int i2 = idx - 65536;
        int c = i2 >> 7, e = i2 & 127;
        WoT[i2] = f2bf(Wout[(size_t)e * 128 + c]);
    } else {
        int i3 = idx - 81920;
        int c = i3 >> 7, e = i3 & 127;
        WbT16[i3] = (c < 4) ? f2bf(Wb[(size_t)e * 4 + c]) : (ushort)0;
    }
}

// ---------------- K1: fused LN + bias-MFMA + x @ [Wqkv|Wg] MFMA GEMM -------
__global__ __launch_bounds__(256) void k_lnqkvg(
    const float* __restrict__ edges, const float* __restrict__ gamma,
    const float* __restrict__ beta,  const ushort* __restrict__ WbT16,
    const ushort* __restrict__ WT,   const float* __restrict__ bg,
    ushort* __restrict__ Bo16,
    ushort* __restrict__ Qo, ushort* __restrict__ Ko,
    ushort* __restrict__ Vo, ushort* __restrict__ Go)
{
    __shared__ __align__(16) ushort As[64][136];
    __shared__ __align__(16) ushort Bs[128][136];
    const int tid = threadIdx.x, w = tid >> 6, lane = tid & 63;
    const int lr = lane & 15, lg = lane >> 4;
    const int wm = w >> 1, wn = w & 1;
    const int p0 = blockIdx.x * 64;
    const f32x4 zz = {0.f, 0.f, 0.f, 0.f};

    // --- LN phase (loop-free): row = w*16+lr, part = lg ---
    {
        const int row = w * 16 + lr;
        const int part = lg;
        const float* ep = edges + (size_t)(p0 + row) * DD + part * 32;
        float4 xv[8];
        #pragma unroll
        for (int t = 0; t < 8; ++t)
            xv[t] = *reinterpret_cast<const float4*>(ep + t * 4);
        float s = 0.f, ss = 0.f;
        #pragma unroll
        for (int t = 0; t < 8; ++t) {
            s  += (xv[t].x + xv[t].y) + (xv[t].z + xv[t].w);
            ss += (xv[t].x * xv[t].x + xv[t].y * xv[t].y)
                + (xv[t].z * xv[t].z + xv[t].w * xv[t].w);
        }
        s  += __shfl_xor(s, 16);  s  += __shfl_xor(s, 32);
        ss += __shfl_xor(ss, 16); ss += __shfl_xor(ss, 32);
        const float mu = s * 0.0078125f;
        const float var = ss * 0.0078125f - mu * mu;
        const float rstd = rsqrtf(var + 1e-5f);
        const float* gp = gamma + part * 32;
        const float* bp = beta + part * 32;
        #pragma unroll
        for (int u = 0; u < 4; ++u) {
            float4 a = xv[2 * u], b = xv[2 * u + 1];
            float4 ga = *reinterpret_cast<const float4*>(gp + u * 8);
            float4 gb = *reinterpret_cast<const float4*>(gp + u * 8 + 4);
            float4 ba = *reinterpret_cast<const float4*>(bp + u * 8);
            float4 bb = *reinterpret_cast<const float4*>(bp + u * 8 + 4);
            float cg;
            uint4 st;
            float v0, v1;
            cg = rstd * ga.x; v0 = a.x * cg + (ba.x - mu * cg);
            cg = rstd * ga.y; v1 = a.y * cg + (ba.y - mu * cg);
            st.x = packbf(v0, v1);
            cg = rstd * ga.z; v0 = a.z * cg + (ba.z - mu * cg);
            cg = rstd * ga.w; v1 = a.w * cg + (ba.w - mu * cg);
            st.y = packbf(v0, v1);
            cg = rstd * gb.x; v0 = b.x * cg + (bb.x - mu * cg);
            cg = rstd * gb.y; v1 = b.y * cg + (bb.y - mu * cg);
            st.z = packbf(v0, v1);
            cg = rstd * gb.z; v0 = b.z * cg + (bb.z - mu * cg);
            cg = rstd * gb.w; v1 = b.w * cg + (bb.w - mu * cg);
            st.w = packbf(v0, v1);
            *reinterpret_cast<uint4*>(&As[row][part * 32 + u * 8]) = st;
        }
    }
    // --- bias via MFMA: wave reads ONLY its own 16 rows (no barrier) ---
    {
        f32x4 bacc = zz;
        #pragma unroll
        for (int kk = 0; kk < 4; ++kk) {
            bf16x8 wb = *reinterpret_cast<const bf16x8*>(&WbT16[(size_t)lr * DD + kk * 32 + lg * 8]);
            bf16x8 xf = *reinterpret_cast<const bf16x8*>(&As[w * 16 + lr][kk * 32 + lg * 8]);
            bacc = mfma16(wb, xf, bacc);   // out[c=4lg+r][p=w*16+lr]
        }
        if (lg == 0) {   // c = r < 4 are the valid head columns
            const int p = p0 + w * 16 + lr;
            const int j = p >> 8, k = p & 255;
            const int fn = k >> 4, lgk = (k >> 2) & 3, rr = k & 3;
            const size_t fo = (((size_t)j * 4 + lgk) * 16 + fn) * 4 + rr;
            #pragma unroll
            for (int r = 0; r < 4; ++r)
                Bo16[(size_t)r * 65536 + fo] = f2bf(bacc[r]);
        }
    }

    for (int seg = 0; seg < 4; ++seg) {
        const int n0 = seg * 128;
        __syncthreads();   // seg0: LN done block-wide; seg>0: Bs reads done
        #pragma unroll
        for (int it = 0; it < 8; ++it) {
            int idx = it * 256 + tid;
            int r = idx >> 4, c = (idx & 15) * 8;
            *reinterpret_cast<uint4*>(&Bs[r][c]) =
                *reinterpret_cast<const uint4*>(&WT[(size_t)(n0 + r) * DD + c]);
        }
        __syncthreads();
        f32x4 acc[2][4];
        #pragma unroll
        for (int m = 0; m < 2; ++m)
            #pragma unroll
            for (int n = 0; n < 4; ++n) acc[m][n] = zz;
        #pragma unroll
        for (int kk = 0; kk < 4; ++kk) {
            bf16x8 a0 = *reinterpret_cast<const bf16x8*>(&As[wm * 32 + lr][kk * 32 + lg * 8]);
            bf16x8 a1 = *reinterpret_cast<const bf16x8*>(&As[wm * 32 + 16 + lr][kk * 32 + lg * 8]);
            #pragma unroll
            for (int n = 0; n < 4; ++n) {
                bf16x8 b = *reinterpret_cast<const bf16x8*>(&Bs[wn * 64 + n * 16 + lr][kk * 32 + lg * 8]);
                acc[0][n] = mfma16(b, a0, acc[0][n]);
                acc[1][n] = mfma16(b, a1, acc[1][n]);
            }
        }
        #pragma unroll
        for (int n = 0; n < 4; ++n) {
            const int ccb = wn * 64 + n * 16 + 4 * lg;
            const int hh = (wn * 64 + n * 16) >> 5;
            const int dhb = ccb & 31;
            float4 bg4;
            if (seg == 3) bg4 = *reinterpret_cast<const float4*>(&bg[ccb]);
            #pragma unroll
            for (int m = 0; m < 2; ++m) {
                const int p = p0 + wm * 32 + m * 16 + lr;
                const size_t off = (size_t)hh * HSTR + (size_t)p * 32 + dhb;
                float v0 = acc[m][n][0], v1 = acc[m][n][1];
                float v2 = acc[m][n][2], v3 = acc[m][n][3];
                uint2 st;
                if (seg == 0) {
                    st.x = packbf(v0 * SCALE, v1 * SCALE);
                    st.y = packbf(v2 * SCALE, v3 * SCALE);
                    *reinterpret_cast<uint2*>(&Qo[off]) = st;
                } else if (seg == 1) {
                    st.x = packbf(v0, v1); st.y = packbf(v2, v3);
                    *reinterpret_cast<uint2*>(&Ko[off]) = st;
                } else if (seg == 2) {
                    st.x = packbf(v0, v1); st.y = packbf(v2, v3);
                    *reinterpret_cast<uint2*>(&Vo[off]) = st;
                } else {
                    float s0 = 1.0f / (1.0f + __expf(-(v0 + bg4.x)));
                    float s1 = 1.0f / (1.0f + __expf(-(v1 + bg4.y)));
                    float s2 = 1.0f / (1.0f + __expf(-(v2 + bg4.z)));
                    float s3 = 1.0f / (1.0f + __expf(-(v3 + bg4.w)));
                    st.x = packbf(s0, s1); st.y = packbf(s2, s3);
                    *reinterpret_cast<uint2*>(&Go[off]) = st;
                }
            }
        }
    }
}

// ---------------- K2: attention; 8 waves, 2 j-tiles/wave, gating fused -----
// grid 1024 (one (i,h) per block, 512 threads): h = bid&3, i = bid>>2.
__global__ __launch_bounds__(512, 4) void k_attn10(
    const ushort* __restrict__ Qw, const ushort* __restrict__ Kw,
    const ushort* __restrict__ Vw, const ushort* __restrict__ Gw,
    const ushort* __restrict__ Bo16,
    const int* __restrict__ mask, ushort* __restrict__ OPre)
{
    __shared__ __align__(16) ushort Ks[256][40];   // K rows: 20.0KB
    __shared__ __align__(16) ushort Vt[32][268];   // V^T (key-permuted): 16.75KB
    const int tid = threadIdx.x, w = tid >> 6, lane = tid & 63;
    const int lr = lane & 15, lg = lane >> 4;
    const int bid = blockIdx.x;
    const int h = bid & 3;
    const int i = bid >> 2;
    const int ib = i * NP;
    const size_t base = (size_t)h * HSTR + (size_t)ib * 32;   // + k*32 + dh

    #pragma unroll
    for (int it = 0; it < 2; ++it) {
        int idx = it * 512 + tid;
        int r = idx >> 2, c = (idx & 3) * 8;
        *reinterpret_cast<uint4*>(&Ks[r][c]) =
            *reinterpret_cast<const uint4*>(&Kw[base + (size_t)r * 32 + c]);
    }
    #pragma unroll
    for (int it = 0; it < 4; ++it) {
        int idx = it * 512 + tid;
        int d = idx & 31, k4 = (idx >> 5) * 4;
        int kk4 = (k4 & ~31) | (((k4 >> 2) & 1) << 4) | (((k4 >> 3) & 3) << 2);
        ushort4 v;
        v.x = Vw[base + (size_t)(kk4 + 0) * 32 + d];
        v.y = Vw[base + (size_t)(kk4 + 1) * 32 + d];
        v.z = Vw[base + (size_t)(kk4 + 2) * 32 + d];
        v.w = Vw[base + (size_t)(kk4 + 3) * 32 + d];
        *reinterpret_cast<ushort4*>(&Vt[d][k4]) = v;
    }
    __syncthreads();

    const ushort* bias_h = Bo16 + (size_t)h * 65536;
    const f32x4 zz = {0.f, 0.f, 0.f, 0.f};

    #pragma unroll
    for (int jt = 0; jt < 2; ++jt) {
        const int jb = jt * 128 + w * 16;
        const int jq = jb + lr;             // this lane's softmax row
        bf16x8 q = *reinterpret_cast<const bf16x8*>(&Qw[base + (size_t)jq * 32 + lg * 8]);
        const ushort* bp = bias_h + ((size_t)jq * 4 + lg) * 64;
        f32x4 s[16];
        #pragma unroll
        for (int u = 0; u < 8; ++u) {
            uint4 b4 = *reinterpret_cast<const uint4*>(bp + u * 8);
            f32x4 s0, s1;
            s0[0] = asf(b4.x << 16); s0[1] = asf(b4.x & 0xffff0000u);
            s0[2] = asf(b4.y << 16); s0[3] = asf(b4.y & 0xffff0000u);
            s1[0] = asf(b4.z << 16); s1[1] = asf(b4.z & 0xffff0000u);
            s1[2] = asf(b4.w << 16); s1[3] = asf(b4.w & 0xffff0000u);
            s[2 * u] = s0; s[2 * u + 1] = s1;
        }
        #pragma unroll
        for (int fn = 0; fn < 16; ++fn) {
            bf16x8 a = *reinterpret_cast<const bf16x8*>(&Ks[fn * 16 + lr][lg * 8]);
            s[fn] = mfma16(a, q, s[fn]);    // S^T[k][j]
        }
        float mx = -3.402823466e38f;
        #pragma unroll
        for (int fn = 0; fn < 16; ++fn) {
            float m01 = fmaxf(s[fn][0], s[fn][1]);
            float m23 = fmaxf(s[fn][2], s[fn][3]);
            mx = fmaxf(mx, fmaxf(m01, m23));
        }
        mx = fmaxf(mx, __shfl_xor(mx, 16));
        mx = fmaxf(mx, __shfl_xor(mx, 32));
        float sum = 0.f;
        #pragma unroll
        for (int fn = 0; fn < 16; ++fn) {
            #pragma unroll
            for (int r = 0; r < 4; ++r) {
                float e = __expf(s[fn][r] - mx);
                s[fn][r] = e; sum += e;
            }
        }
        sum += __shfl_xor(sum, 16);
        sum += __shfl_xor(sum, 32);
        const bool masked = (mask[ib + jq] == 0);
        const float iv = masked ? 1.0f : (1.0f / sum);

        f32x4 o0 = zz, o1 = zz;
        #pragma unroll
        for (int m = 0; m < 8; ++m) {
            union { unsigned int u[4]; bf16x8 v; } pa;
            pa.u[0] = masked ? 0x3B803B80u : packbf(s[2 * m][0], s[2 * m][1]);
            pa.u[1] = masked ? 0x3B803B80u : packbf(s[2 * m][2], s[2 * m][3]);
            pa.u[2] = masked ? 0x3B803B80u : packbf(s[2 * m + 1][0], s[2 * m + 1][1]);
            pa.u[3] = masked ? 0x3B803B80u : packbf(s[2 * m + 1][2], s[2 * m + 1][3]);
            bf16x8 v0 = *reinterpret_cast<const bf16x8*>(&Vt[lr][m * 32 + lg * 8]);
            bf16x8 v1 = *reinterpret_cast<const bf16x8*>(&Vt[16 + lr][m * 32 + lg * 8]);
            o0 = mfma16(v0, pa.v, o0);
            o1 = mfma16(v1, pa.v, o1);
        }
        // epilogue: gating fused (dense G reads at same addresses as stores)
        const size_t off = base + (size_t)jq * 32;
        uint2 gv0 = *reinterpret_cast<const uint2*>(&Gw[off + 4 * lg]);
        uint2 gv1 = *reinterpret_cast<const uint2*>(&Gw[off + 16 + 4 * lg]);
        float g0 = masked ? NEGV : bf2f((ushort)(gv0.x & 0xffffu));
        float g1 = masked ? NEGV : bf2f((ushort)(gv0.x >> 16));
        float g2 = masked ? NEGV : bf2f((ushort)(gv0.y & 0xffffu));
        float g3 = masked ? NEGV : bf2f((ushort)(gv0.y >> 16));
        float g4 = masked ? NEGV : bf2f((ushort)(gv1.x & 0xffffu));
        float g5 = masked ? NEGV : bf2f((ushort)(gv1.x >> 16));
        float g6 = masked ? NEGV : bf2f((ushort)(gv1.y & 0xffffu));
        float g7 = masked ? NEGV : bf2f((ushort)(gv1.y >> 16));
        uint2 u0, u1;
        u0.x = packbf(o0[0] * iv * g0, o0[1] * iv * g1);
        u0.y = packbf(o0[2] * iv * g2, o0[3] * iv * g3);
        u1.x = packbf(o1[0] * iv * g4, o1[1] * iv * g5);
        u1.y = packbf(o1[2] * iv * g6, o1[3] * iv * g7);
        *reinterpret_cast<uint2*>(&OPre[off + 4 * lg])      = u0;
        *reinterpret_cast<uint2*>(&OPre[off + 16 + 4 * lg]) = u1;
    }
}

// ---------------- K3: out = OPre @ Wout + bout (OPre pre-gated) ------------
__global__ __launch_bounds__(256) void k_gemm_out(
    const ushort* __restrict__ OPre, const ushort* __restrict__ WoT,
    const float* __restrict__ bout, float* __restrict__ out)
{
    __shared__ __align__(16) ushort As[64][136];
    __shared__ __align__(16) ushort Bs[128][136];
    const int tid = threadIdx.x;
    const int p0 = blockIdx.x * 64;
    #pragma unroll
    for (int it = 0; it < 4; ++it) {
        int idx = it * 256 + tid;
        int r = idx >> 4, c = (idx & 15) * 8;
        int hh = c >> 5, dq = c & 31;
        const int p = p0 + r;
        const size_t go = (size_t)hh * HSTR + (size_t)p * 32 + dq;
        *reinterpret_cast<uint4*>(&As[r][c]) =
            *reinterpret_cast<const uint4*>(&OPre[go]);
    }
    #pragma unroll
    for (int it = 0; it < 8; ++it) {
        int idx = it * 256 + tid;
        int r = idx >> 4, c = (idx & 15) * 8;
        *reinterpret_cast<uint4*>(&Bs[r][c]) =
            *reinterpret_cast<const uint4*>(&WoT[(size_t)r * DD + c]);
    }
    __syncthreads();
    const int w = tid >> 6, lane = tid & 63;
    const int wm = w >> 1, wn = w & 1;
    const int lr = lane & 15, lg = lane >> 4;
    const f32x4 zz = {0.f, 0.f, 0.f, 0.f};
    f32x4 acc[2][4];
    #pragma unroll
    for (int m = 0; m < 2; ++m)
        #pragma unroll
        for (int n = 0; n < 4; ++n) acc[m][n] = zz;
    #pragma unroll
    for (int kk = 0; kk < 4; ++kk) {
        bf16x8 a0 = *reinterpret_cast<const bf16x8*>(&As[wm * 32 + lr][kk * 32 + lg * 8]);
        bf16x8 a1 = *reinterpret_cast<const bf16x8*>(&As[wm * 32 + 16 + lr][kk * 32 + lg * 8]);
        #pragma unroll
        for (int n = 0; n < 4; ++n) {
            bf16x8 b = *reinterpret_cast<const bf16x8*>(&Bs[wn * 64 + n * 16 + lr][kk * 32 + lg * 8]);
            // swapped: out[c = wn*64+n*16+4lg+r][p = wm*32+(m*16)+lr]
            acc[0][n] = mfma16(b, a0, acc[0][n]);
            acc[1][n] = mfma16(b, a1, acc[1][n]);
        }
    }
    #pragma unroll
    for (int n = 0; n < 4; ++n) {
        const int cb = wn * 64 + n * 16 + 4 * lg;
        const float4 bo4 = *reinterpret_cast<const float4*>(&bout[cb]);
        #pragma unroll
        for (int m = 0; m < 2; ++m) {
            const int p = p0 + wm * 32 + m * 16 + lr;
            float4 st;
            st.x = acc[m][n][0] + bo4.x;
            st.y = acc[m][n][1] + bo4.y;
            st.z = acc[m][n][2] + bo4.z;
            st.w = acc[m][n][3] + bo4.w;
            *reinterpret_cast<float4*>(&out[(size_t)p * DD + cb]) = st;
        }
    }
}

extern "C" void kernel_launch(void* const* d_in, const int* in_sizes, int n_in,
                              void* d_out, int out_size, void* d_ws, size_t ws_size,
                              hipStream_t stream) {
    const float* edges = (const float*)d_in[0];
    const int*   mask  = (const int*)d_in[1];
    const float* gamma = (const float*)d_in[2];
    const float* beta  = (const float*)d_in[3];
    const float* Wqkv  = (const float*)d_in[4];
    const float* Wb    = (const float*)d_in[5];
    const float* Wg    = (const float*)d_in[6];
    const float* bg    = (const float*)d_in[7];
    const float* Wout  = (const float*)d_in[8];
    const float* bout  = (const float*)d_in[9];
    float* out = (float*)d_out;

    char* ws = (char*)d_ws;
    ushort* OPre = (ushort*)(ws);                              // 16 MiB (head-blocked, gated)
    ushort* Qw  = (ushort*)(ws + 1u * 16777216u);              // head-blocked
    ushort* Kw  = (ushort*)(ws + 2u * 16777216u);
    ushort* Vw  = (ushort*)(ws + 3u * 16777216u);
    ushort* Gw  = (ushort*)(ws + 4u * 16777216u);
    ushort* Bo16 = (ushort*)(ws + 5u * 16777216u);                     // 512 KiB bf16
    ushort* WT  = (ushort*)(ws + 5u * 16777216u + 524288u);            // 128 KiB
    ushort* WoT = (ushort*)(ws + 5u * 16777216u + 524288u + 131072u);  // 32 KiB
    ushort* WbT16 = (ushort*)(ws + 5u * 16777216u + 524288u + 131072u + 32768u); // 4 KiB

    k_wconv<<<dim3(328), dim3(256), 0, stream>>>(Wqkv, Wg, Wout, Wb, WT, WoT, WbT16);
    k_lnqkvg<<<dim3(1024), dim3(256), 0, stream>>>(edges, gamma, beta, WbT16, WT, bg,
                                                   Bo16, Qw, Kw, Vw, Gw);
    k_attn10<<<dim3(1024), dim3(512), 0, stream>>>(Qw, Kw, Vw, Gw, Bo16, mask, OPre);
    k_gemm_out<<<dim3(1024), dim3(256), 0, stream>>>(OPre, WoT, bout, out);
}